// Round 4
// baseline (208.574 us; speedup 1.0000x reference)
//
#include <hip/hip_runtime.h>
#include <hip/hip_bf16.h>

// LSTM: SEQ=64, IN=100000, H=50 (4H=200 gates)
// x[64,100000] f32, Wi[100000,200] f32, bi[200], Wh[50,200], bh[200] -> h[50]
//
// K1: split-K GEMM C[64,200] = x @ Wi.
//     lane = float4 g-col (50 active), wave = 8 s-rows.
//     W tile in LDS (1 b128 per wave-k, conflict-free contiguous reads).
//     x via SCALAR loads (wave-uniform rows, readfirstlane-anchored) ->
//     s_load_dwordx4 double-buffered in SGPRs; FMA = VGPR(W) x SGPR(x).
//     LDS pipe: 1 instr / 32 FMA  (round-3 was 3/32 and LDS-bound at 47us).
// K2: reduce 512 partials + bi + bh -> gates[s*200+g]  (512 thr, 8 slices)
// K3: 64-step recurrence, single block, gates staged in LDS.

#define K_DIM 100000
#define NG 200
#define NS 64
#define TK 32                    // 100000 = 32 * 3125, so all tiles full
#define NBLK 512
#define KSTRIDE (NBLK * TK)      // 16384
#define CELLS (NS * NG)          // 12800

__global__ __launch_bounds__(512, 4) void k1_gemm_partial(
    const float* __restrict__ x, const float* __restrict__ Wi,
    float* __restrict__ partial)
{
    __shared__ float4 ws4[TK * 50 + 16];     // +16 pad: lanes 50-63 read garbage safely

    const int tid  = threadIdx.x;
    const int lane = tid & 63;               // f4 g-col, stores only if < 50
    const int wave = tid >> 6;               // 0..7, owns s rows 8w..8w+7
    const int s0u  = __builtin_amdgcn_readfirstlane(wave * 8);  // force SGPR

    float4 acc4[8];
#pragma unroll
    for (int j = 0; j < 8; ++j) acc4[j] = make_float4(0.f, 0.f, 0.f, 0.f);

    int kt = blockIdx.x * TK;
    const float4* wi4 = (const float4*)Wi;

    // prefetch first W tile (coalesced float4, 1600 f4 by 512 threads)
    float4 w0, w1, w2, w3 = make_float4(0.f, 0.f, 0.f, 0.f);
    {
        const float4* wt = wi4 + (size_t)kt * 50;
        w0 = wt[tid];
        w1 = wt[tid + 512];
        w2 = wt[tid + 1024];
        if (tid < 64) w3 = wt[tid + 1536];
    }

    for (; kt < K_DIM; kt += KSTRIDE) {
        __syncthreads();                     // previous tile's readers done
        ws4[tid]        = w0;
        ws4[tid + 512]  = w1;
        ws4[tid + 1024] = w2;
        if (tid < 64) ws4[tid + 1536] = w3;
        __syncthreads();

        // issue next W tile's global loads; latency hides behind compute
        int ktn = kt + KSTRIDE;
        if (ktn < K_DIM) {
            const float4* wt = wi4 + (size_t)ktn * 50;
            w0 = wt[tid];
            w1 = wt[tid + 512];
            w2 = wt[tid + 1024];
            if (tid < 64) w3 = wt[tid + 1536];
        }

        // x tile for this wave: rows s0u..s0u+7, k = kt..kt+31, all wave-uniform
        // -> scalar loads (s_load_dwordx4), double-buffered 4-k batches.
        const float* xt = x + (size_t)s0u * K_DIM + kt;
        float4 xc[8], xn[8];
#pragma unroll
        for (int i = 0; i < 8; ++i)
            xc[i] = *(const float4*)(xt + (size_t)i * K_DIM);

#pragma unroll
        for (int k4 = 0; k4 < TK / 4; ++k4) {
            if (k4 + 1 < TK / 4) {
#pragma unroll
                for (int i = 0; i < 8; ++i)
                    xn[i] = *(const float4*)(xt + (size_t)i * K_DIM + (k4 + 1) * 4);
            }
#pragma unroll
            for (int kk = 0; kk < 4; ++kk) {
                float4 wv = ws4[(k4 * 4 + kk) * 50 + lane];   // 1 b128 / 32 FMA
#pragma unroll
                for (int i = 0; i < 8; ++i) {
                    float xv = (kk == 0) ? xc[i].x : (kk == 1) ? xc[i].y
                             : (kk == 2) ? xc[i].z : xc[i].w;   // SGPR operand
                    acc4[i].x = fmaf(wv.x, xv, acc4[i].x);
                    acc4[i].y = fmaf(wv.y, xv, acc4[i].y);
                    acc4[i].z = fmaf(wv.z, xv, acc4[i].z);
                    acc4[i].w = fmaf(wv.w, xv, acc4[i].w);
                }
            }
            if (k4 + 1 < TK / 4) {
#pragma unroll
                for (int i = 0; i < 8; ++i) xc[i] = xn[i];
            }
        }
    }

    // partial[b][s][g]: f4 stores, 50 lanes x 16B contiguous = coalesced
    if (lane < 50) {
        float4* pout = (float4*)(partial + (size_t)blockIdx.x * CELLS) + lane;
#pragma unroll
        for (int si = 0; si < 8; ++si)
            pout[(s0u + si) * 50] = acc4[si];
    }
}

__global__ __launch_bounds__(512) void k2_reduce(
    const float* __restrict__ partial, const float* __restrict__ bi,
    const float* __restrict__ bh, float* __restrict__ gates)
{
    __shared__ float red[512];
    const int tid   = threadIdx.x;
    const int lane  = tid & 63;
    const int slice = tid >> 6;                 // 0..7, each sums 64 b's
    const int cell  = blockIdx.x * 64 + lane;   // = s*200 + g

    float sum = 0.f;
#pragma unroll 8
    for (int b = slice * 64; b < (slice + 1) * 64; ++b)
        sum += partial[(size_t)b * CELLS + cell];
    red[tid] = sum;
    __syncthreads();
    if (slice == 0) {
        float tot = red[lane];
#pragma unroll
        for (int p = 1; p < 8; ++p) tot += red[p * 64 + lane];
        int g = cell % NG;
        gates[cell] = tot + bi[g] + bh[g];
    }
}

__global__ __launch_bounds__(256) void k3_lstm(
    const float* __restrict__ gates, const float* __restrict__ Wh,
    float* __restrict__ out)
{
    __shared__ float gz[CELLS];     // 51.2 KB: all gate pre-activations
    __shared__ float h_lds[64];
    __shared__ float act_lds[NG];
    const int g = threadIdx.x;      // gate index, active < 200

    // stage gates -> LDS (coalesced); step loop then touches no global memory
    for (int i = g; i < CELLS; i += 256) gz[i] = gates[i];

    float wh[50];
    if (g < NG) {
#pragma unroll
        for (int j = 0; j < 50; ++j) wh[j] = Wh[j * NG + g];  // coalesced column
    }
    if (g < 64) h_lds[g] = 0.f;
    float c = 0.f, h = 0.f;
    const bool is_cell_gate = (g >= 100 && g < 150);
    __syncthreads();

    for (int s = 0; s < 64; ++s) {
        if (g < NG) {
            float a0 = gz[s * NG + g];
            float a1 = 0.f;
#pragma unroll
            for (int jj = 0; jj < 50; jj += 2) {
                float2 h2 = *(const float2*)(h_lds + jj);  // LDS broadcast
                a0 = fmaf(h2.x, wh[jj],     a0);
                a1 = fmaf(h2.y, wh[jj + 1], a1);
            }
            float z = a0 + a1;
            float e   = __expf(-z);
            float sig = 1.f / (1.f + e);
            float e2  = e * e;                        // e^{-2z}
            float th  = (1.f - e2) / (1.f + e2);
            act_lds[g] = is_cell_gate ? th : sig;
        }
        __syncthreads();
        if (g < 50) {
            float iv = act_lds[g];
            float fv = act_lds[50 + g];
            float gv = act_lds[100 + g];
            float ov = act_lds[150 + g];
            c = fmaf(fv, c, iv * gv);
            float e2c = __expf(-2.f * c);
            h = ov * (1.f - e2c) / (1.f + e2c);
            h_lds[g] = h;
        }
        __syncthreads();
    }
    if (g < 50) out[g] = h;
}

extern "C" void kernel_launch(void* const* d_in, const int* in_sizes, int n_in,
                              void* d_out, int out_size, void* d_ws, size_t ws_size,
                              hipStream_t stream)
{
    const float* x  = (const float*)d_in[0];
    const float* Wi = (const float*)d_in[1];
    const float* bi = (const float*)d_in[2];
    const float* Wh = (const float*)d_in[3];
    const float* bh = (const float*)d_in[4];
    float* out = (float*)d_out;

    float* partial = (float*)d_ws;                    // 512*12800 f32 = 26.2 MB
    float* gates   = partial + (size_t)NBLK * CELLS;  // 12800 f32

    k1_gemm_partial<<<NBLK, 512, 0, stream>>>(x, Wi, partial);
    k2_reduce<<<CELLS / 64, 512, 0, stream>>>(partial, bi, bh, gates);
    k3_lstm<<<1, 256, 0, stream>>>(gates, Wh, out);
}

// Round 5
// 207.845 us; speedup vs baseline: 1.0035x; 1.0035x over previous
//
#include <hip/hip_runtime.h>
#include <hip/hip_bf16.h>

// LSTM: SEQ=64, IN=100000, H=50 (4H=200 gates)
// x[64,100000] f32, Wi[100000,200] f32, bi[200], Wh[50,200], bh[200] -> h[50]
//
// K1: split-K GEMM C[64,200] = x @ Wi.
//     lane = float4 g-col (50 active), wave = 8 s-rows.
//     W tile in LDS (1 b128 per wave-k). x tile loaded as 1 float4/lane
//     (vector path), then splatted with v_readlane (compile-time lane idx):
//     per wave-k = 1 LDS + 8 readlane + 32 FMA, zero scalar-mem, zero x-LDS.
//     (R3 was LDS-bound at 3 LDS/32FMA; R4 scalar s_load path K$-thrashed.)
// K2: reduce 512 partials + bi + bh -> gates, all float4.
// K3: 64-step recurrence, single block, gates in LDS, h read as float4.

#define K_DIM 100000
#define NG 200
#define NS 64
#define TK 32                    // 100000 % 32 == 0
#define NBLK 512
#define KSTRIDE (NBLK * TK)      // 16384
#define CELLS (NS * NG)          // 12800
#define CELLS4 (CELLS / 4)       // 3200

static __device__ __forceinline__ float rl(float v, int l) {
    return __int_as_float(__builtin_amdgcn_readlane(__float_as_int(v), l));
}

__global__ __launch_bounds__(512, 4) void k1_gemm_partial(
    const float* __restrict__ x, const float* __restrict__ Wi,
    float* __restrict__ partial)
{
    __shared__ float4 ws4[TK * 50 + 16];     // +16 pad: lanes 50-63 read garbage safely

    const int tid  = threadIdx.x;
    const int lane = tid & 63;               // f4 g-col, stores only if < 50
    const int wave = tid >> 6;               // 0..7, owns s rows 8w..8w+7
    const int s0   = wave * 8;

    // x tile layout in regs: lane r*8+q holds x[s0+r][kt + 4q .. 4q+3]
    const int xrow  = s0 + (lane >> 3);
    const int xkoff = (lane & 7) << 2;
    const float* xbase = x + (size_t)xrow * K_DIM + xkoff;

    float4 acc4[8];
#pragma unroll
    for (int j = 0; j < 8; ++j) acc4[j] = make_float4(0.f, 0.f, 0.f, 0.f);

    int kt = blockIdx.x * TK;
    const float4* wi4 = (const float4*)Wi;

    // prefetch first tiles (coalesced)
    float4 w0, w1, w2, w3 = make_float4(0.f, 0.f, 0.f, 0.f), xc, xn;
    {
        const float4* wt = wi4 + (size_t)kt * 50;
        w0 = wt[tid];
        w1 = wt[tid + 512];
        w2 = wt[tid + 1024];
        if (tid < 64) w3 = wt[tid + 1536];
        xc = *(const float4*)(xbase + kt);
    }

    for (; kt < K_DIM; kt += KSTRIDE) {
        __syncthreads();                     // previous tile's W readers done
        ws4[tid]        = w0;
        ws4[tid + 512]  = w1;
        ws4[tid + 1024] = w2;
        if (tid < 64) ws4[tid + 1536] = w3;
        __syncthreads();

        // issue next tiles' global loads; latency hides behind compute
        int ktn = kt + KSTRIDE;
        if (ktn < K_DIM) {
            const float4* wt = wi4 + (size_t)ktn * 50;
            w0 = wt[tid];
            w1 = wt[tid + 512];
            w2 = wt[tid + 1024];
            if (tid < 64) w3 = wt[tid + 1536];
            xn = *(const float4*)(xbase + ktn);
        }

#pragma unroll
        for (int q = 0; q < 8; ++q) {
#pragma unroll
            for (int kk = 0; kk < 4; ++kk) {
                float4 wv = ws4[(q * 4 + kk) * 50 + lane];     // 1 b128 / 32 FMA
                float xcomp = (kk == 0) ? xc.x : (kk == 1) ? xc.y
                            : (kk == 2) ? xc.z : xc.w;
#pragma unroll
                for (int r = 0; r < 8; ++r) {
                    float xv = rl(xcomp, r * 8 + q);           // splat -> SGPR
                    acc4[r].x = fmaf(wv.x, xv, acc4[r].x);
                    acc4[r].y = fmaf(wv.y, xv, acc4[r].y);
                    acc4[r].z = fmaf(wv.z, xv, acc4[r].z);
                    acc4[r].w = fmaf(wv.w, xv, acc4[r].w);
                }
            }
        }
        xc = xn;
    }

    // partial[b][s][g]: f4 stores, 50 lanes x 16B contiguous = coalesced
    if (lane < 50) {
        float4* pout = (float4*)(partial + (size_t)blockIdx.x * CELLS) + lane;
#pragma unroll
        for (int si = 0; si < 8; ++si)
            pout[(s0 + si) * 50] = acc4[si];
    }
}

__global__ __launch_bounds__(512) void k2_reduce(
    const float* __restrict__ partial, const float* __restrict__ bi,
    const float* __restrict__ bh, float* __restrict__ gates)
{
    __shared__ float4 red[512];
    const int tid   = threadIdx.x;
    const int fid   = tid & 15;                 // f4-cell within block
    const int slice = tid >> 4;                 // 0..31, each sums 16 b's
    const int g4    = blockIdx.x * 16 + fid;    // 0..3199

    const float4* p4 = (const float4*)partial;
    float4 sum = make_float4(0.f, 0.f, 0.f, 0.f);
#pragma unroll 4
    for (int b = slice * 16; b < slice * 16 + 16; ++b) {
        float4 v = p4[(size_t)b * CELLS4 + g4];
        sum.x += v.x; sum.y += v.y; sum.z += v.z; sum.w += v.w;
    }
    red[tid] = sum;
    __syncthreads();
    if (tid < 16) {
        float4 tot = red[tid];
#pragma unroll
        for (int p = 1; p < 32; ++p) {
            float4 v = red[p * 16 + tid];
            tot.x += v.x; tot.y += v.y; tot.z += v.z; tot.w += v.w;
        }
        int gg = (g4 * 4) % NG;                 // NG%4==0: never wraps mid-f4
        float4 b1 = *(const float4*)(bi + gg);
        float4 b2 = *(const float4*)(bh + gg);
        tot.x += b1.x + b2.x; tot.y += b1.y + b2.y;
        tot.z += b1.z + b2.z; tot.w += b1.w + b2.w;
        ((float4*)gates)[g4] = tot;
    }
}

__global__ __launch_bounds__(256) void k3_lstm(
    const float* __restrict__ gates, const float* __restrict__ Wh,
    float* __restrict__ out)
{
    __shared__ float gz[CELLS];     // 51.2 KB: all gate pre-activations
    __shared__ float h_lds[64];     // 16B-aligned
    __shared__ float act_lds[NG];
    const int g = threadIdx.x;      // gate index, active < 200

    // stage gates -> LDS (coalesced); step loop then touches no global memory
    for (int i = g; i < CELLS; i += 256) gz[i] = gates[i];

    float wh[50];
    if (g < NG) {
#pragma unroll
        for (int j = 0; j < 50; ++j) wh[j] = Wh[j * NG + g];  // coalesced column
    }
    if (g < 64) h_lds[g] = 0.f;
    float c = 0.f, h = 0.f;
    const bool is_cell_gate = (g >= 100 && g < 150);
    __syncthreads();

    for (int s = 0; s < 64; ++s) {
        if (g < NG) {
            float a0 = gz[s * NG + g], a1 = 0.f, a2 = 0.f, a3 = 0.f;
#pragma unroll
            for (int jj = 0; jj < 48; jj += 4) {               // 12x b128 broadcast
                float4 h4 = *(const float4*)(h_lds + jj);
                a0 = fmaf(h4.x, wh[jj],     a0);
                a1 = fmaf(h4.y, wh[jj + 1], a1);
                a2 = fmaf(h4.z, wh[jj + 2], a2);
                a3 = fmaf(h4.w, wh[jj + 3], a3);
            }
            {
                float2 h2 = *(const float2*)(h_lds + 48);      // 1x b64
                a0 = fmaf(h2.x, wh[48], a0);
                a1 = fmaf(h2.y, wh[49], a1);
            }
            float z = (a0 + a1) + (a2 + a3);
            float e   = __expf(-z);
            float sig = 1.f / (1.f + e);
            float e2  = e * e;                        // e^{-2z}
            float th  = (1.f - e2) / (1.f + e2);
            act_lds[g] = is_cell_gate ? th : sig;
        }
        __syncthreads();
        if (g < 50) {
            float iv = act_lds[g];
            float fv = act_lds[50 + g];
            float gv = act_lds[100 + g];
            float ov = act_lds[150 + g];
            c = fmaf(fv, c, iv * gv);
            float e2c = __expf(-2.f * c);
            h = ov * (1.f - e2c) / (1.f + e2c);
            h_lds[g] = h;
        }
        __syncthreads();
    }
    if (g < 50) out[g] = h;
}

extern "C" void kernel_launch(void* const* d_in, const int* in_sizes, int n_in,
                              void* d_out, int out_size, void* d_ws, size_t ws_size,
                              hipStream_t stream)
{
    const float* x  = (const float*)d_in[0];
    const float* Wi = (const float*)d_in[1];
    const float* bi = (const float*)d_in[2];
    const float* Wh = (const float*)d_in[3];
    const float* bh = (const float*)d_in[4];
    float* out = (float*)d_out;

    float* partial = (float*)d_ws;                    // 512*12800 f32 = 26.2 MB
    float* gates   = partial + (size_t)NBLK * CELLS;  // 12800 f32

    k1_gemm_partial<<<NBLK, 512, 0, stream>>>(x, Wi, partial);
    k2_reduce<<<CELLS4 / 16, 512, 0, stream>>>(partial, bi, bh, gates);
    k3_lstm<<<1, 256, 0, stream>>>(gates, Wh, out);
}

// Round 6
// 188.601 us; speedup vs baseline: 1.1059x; 1.1020x over previous
//
#include <hip/hip_runtime.h>
#include <hip/hip_bf16.h>

// LSTM: SEQ=64, IN=100000, H=50 (4H=200 gates)
// x[64,100000] f32, Wi[100000,200] f32, bi[200], Wh[50,200], bh[200] -> h[50]
//
// K1: split-K GEMM via MFMA 32x32x16 bf16, hi/lo-split fp32 emulation:
//     f = hi(bf16 trunc) + lo(bf16 rne of remainder); x*w = xh*wh + xh*wl + xl*wh
//     -> ~2^-17 rel err (fp32-class). 3 MFMA per tile-kstep, still memory-bound.
//     Tiles: C[64 s][224 g-pad] = 2 s-tiles x 7 g-tiles of 32.
//     Block 256 thr = 4 waves: wave w -> s-tile (w>>1), g-set (w&1): {0..3} / {4..6}.
//     Wi transposed 4x4 in-registers -> LDS [g][k] rows (80B stride, b128 frags).
// K2: reduce 512 partials + bi + bh -> gates[s*200+g]
// K3: 64-step recurrence, single block, gates in LDS.

#define K_DIM 100000
#define NG 200
#define NS 64
#define TK 32                    // 100000 = 32 * 3125 exactly
#define NBLK 512
#define NTILES 3125              // K_DIM / TK
#define CELLS (NS * NG)          // 12800
#define CELLS4 (CELLS / 4)       // 3200
#define ROWU 40                  // u16 per LDS row = 32 k + 8 pad = 80 B (16B-aligned)

typedef unsigned short u16;
typedef unsigned int   u32;
typedef __bf16 bf16x8 __attribute__((ext_vector_type(8)));
typedef float  f32x16 __attribute__((ext_vector_type(16)));

static __device__ __forceinline__ u32 rne16(float f) {
    u32 u = __float_as_uint(f);
    return (u + 0x7FFFu + ((u >> 16) & 1u)) >> 16;
}
static __device__ __forceinline__ void split_hl(float f, u32& h, u32& l) {
    u32 u  = __float_as_uint(f);
    u32 hb = u & 0xFFFF0000u;
    h = hb >> 16;
    l = rne16(f - __uint_as_float(hb));   // remainder is exact; rne to bf16
}
static __device__ __forceinline__ void split4(float4 v, u32 h[4], u32 l[4]) {
    split_hl(v.x, h[0], l[0]); split_hl(v.y, h[1], l[1]);
    split_hl(v.z, h[2], l[2]); split_hl(v.w, h[3], l[3]);
}
static __device__ __forceinline__ f32x16 mfma_bf(uint4 a, uint4 b, f32x16 c) {
    return __builtin_amdgcn_mfma_f32_32x32x16_bf16(
        __builtin_bit_cast(bf16x8, a), __builtin_bit_cast(bf16x8, b), c, 0, 0, 0);
}

__global__ __launch_bounds__(256, 2) void k1_gemm_partial(
    const float* __restrict__ x, const float* __restrict__ Wi,
    float* __restrict__ partial)
{
    __shared__ __align__(16) u16 WH[224 * ROWU];   // Wi hi, [g][k]  17.9 KB
    __shared__ __align__(16) u16 WL[224 * ROWU];   // Wi lo
    __shared__ __align__(16) u16 XH[64 * ROWU];    // x  hi, [s][k]   5.1 KB
    __shared__ __align__(16) u16 XL[64 * ROWU];    // x  lo          total 46 KB

    const int t    = threadIdx.x;
    const int lane = t & 63;
    const int wave = t >> 6;
    const int m    = lane & 31;          // MFMA row/col within tile
    const int h    = lane >> 5;          // k-half
    const int stile = wave >> 1;         // 0..1
    const int gset  = wave & 1;          // 0: g-tiles 0..3, 1: 4..6(+dup)

    // zero Wi pad rows 200..223 once (never rewritten; g-tile 6 cols 8..31 -> 0)
    {
        u32* zh = (u32*)&WH[200 * ROWU];
        u32* zl = (u32*)&WL[200 * ROWU];
        for (int i = t; i < 24 * ROWU / 2; i += 256) { zh[i] = 0; zl[i] = 0; }
    }

    // ---- Wi staging task decode (tasks = 50 g4 x 8 k4 = 400) ----
    // taskA: tau=t (g4 0..31); taskB: t<128 -> tau=t+256 (g4 32..47);
    //        t>=240 -> tail (g4 48..49 x k4 0..7)
    const int a_g4 = (t & 7) + 8 * ((t >> 6) & 3);
    const int a_k4 = (t >> 3) & 7;
    int b_g4 = -1, b_k4 = 0;
    if (t < 128)      { int tau = t + 256; b_g4 = (tau & 7) + 8 * (tau >> 6); b_k4 = (tau >> 3) & 7; }
    else if (t >= 240){ int idx = t - 240; b_g4 = 48 + (idx & 1); b_k4 = idx >> 1; }
    // x staging: phi = t, t+256: s = phi>>3, k4 = phi&7
    const int xs0 = t >> 3, xk0 = t & 7;       // phi = t
    const int xs1 = (t + 256) >> 3, xk1 = t & 7; // phi = t+256 (same low bits)

    float4 wa[4], wb[4], xa, xb;
    auto do_loads = [&](int ti) {
        const size_t kt = (size_t)ti * TK;
#pragma unroll
        for (int j = 0; j < 4; ++j)
            wa[j] = *(const float4*)(Wi + (kt + a_k4 * 4 + j) * NG + a_g4 * 4);
        if (b_g4 >= 0) {
#pragma unroll
            for (int j = 0; j < 4; ++j)
                wb[j] = *(const float4*)(Wi + (kt + b_k4 * 4 + j) * NG + b_g4 * 4);
        }
        xa = *(const float4*)(x + (size_t)xs0 * K_DIM + kt + xk0 * 4);
        xb = *(const float4*)(x + (size_t)xs1 * K_DIM + kt + xk1 * 4);
    };
    auto stage_wi = [&](const float4 r[4], int g4, int k4) {
        u32 hw[4][4], lw[4][4];
#pragma unroll
        for (int j = 0; j < 4; ++j) split4(r[j], hw[j], lw[j]);
#pragma unroll
        for (int j2 = 0; j2 < 4; ++j2) {   // transpose: row g=4g4+j2 gets 4 k's
            int off = (4 * g4 + j2) * ROWU + k4 * 4;
            *(uint2*)&WH[off] = make_uint2(hw[0][j2] | (hw[1][j2] << 16),
                                           hw[2][j2] | (hw[3][j2] << 16));
            *(uint2*)&WL[off] = make_uint2(lw[0][j2] | (lw[1][j2] << 16),
                                           lw[2][j2] | (lw[3][j2] << 16));
        }
    };
    auto stage_x = [&](float4 v, int s, int k4) {
        u32 hh[4], ll[4];
        split4(v, hh, ll);
        int off = s * ROWU + k4 * 4;
        *(uint2*)&XH[off] = make_uint2(hh[0] | (hh[1] << 16), hh[2] | (hh[3] << 16));
        *(uint2*)&XL[off] = make_uint2(ll[0] | (ll[1] << 16), ll[2] | (ll[3] << 16));
    };

    f32x16 acc[4];
#pragma unroll
    for (int tt = 0; tt < 4; ++tt)
#pragma unroll
        for (int r = 0; r < 16; ++r) acc[tt][r] = 0.f;

    // fragment LDS offsets (u16 units)
    const int aoff = (stile * 32 + m) * ROWU + h * 8;
    int boff[4];
#pragma unroll
    for (int tt = 0; tt < 4; ++tt) {
        int gt = gset ? (4 + (tt == 3 ? 2 : tt)) : tt;   // gset1 tt3 dups tile 6
        boff[tt] = (gt * 32 + m) * ROWU + h * 8;
    }

    do_loads(blockIdx.x);
    for (int ti = blockIdx.x; ti < NTILES; ti += NBLK) {
        __syncthreads();                 // previous stage's frag readers done
        stage_wi(wa, a_g4, a_k4);
        if (b_g4 >= 0) stage_wi(wb, b_g4, b_k4);
        stage_x(xa, xs0, xk0);
        stage_x(xb, xs1, xk1);
        __syncthreads();

        int tin = ti + NBLK;
        if (tin < NTILES) do_loads(tin); // latency hides behind MFMA phase

#pragma unroll
        for (int kk = 0; kk < 2; ++kk) {
            uint4 ah = *(const uint4*)&XH[aoff + kk * 16];
            uint4 al = *(const uint4*)&XL[aoff + kk * 16];
#pragma unroll
            for (int tt = 0; tt < 4; ++tt) {
                uint4 bh = *(const uint4*)&WH[boff[tt] + kk * 16];
                uint4 bl = *(const uint4*)&WL[boff[tt] + kk * 16];
                acc[tt] = mfma_bf(ah, bh, acc[tt]);   // xh*wh
                acc[tt] = mfma_bf(ah, bl, acc[tt]);   // xh*wl
                acc[tt] = mfma_bf(al, bh, acc[tt]);   // xl*wh
            }
        }
    }

    // epilogue: partial[b][s][g]; C/D: col=lane&31, row=(r&3)+8(r>>2)+4h
    float* base = partial + (size_t)blockIdx.x * CELLS;
#pragma unroll
    for (int tt = 0; tt < 4; ++tt) {
        if (gset && tt == 3) continue;   // duplicate tile
        int g = (gset ? 4 + tt : tt) * 32 + m;
        if (g < NG) {
#pragma unroll
            for (int r = 0; r < 16; ++r) {
                int srow = stile * 32 + (r & 3) + 8 * (r >> 2) + 4 * h;
                base[srow * NG + g] = acc[tt][r];
            }
        }
    }
}

__global__ __launch_bounds__(512) void k2_reduce(
    const float* __restrict__ partial, const float* __restrict__ bi,
    const float* __restrict__ bh, float* __restrict__ gates)
{
    __shared__ float4 red[512];
    const int tid   = threadIdx.x;
    const int fid   = tid & 15;                 // f4-cell within block
    const int slice = tid >> 4;                 // 0..31, each sums 16 b's
    const int g4    = blockIdx.x * 16 + fid;    // 0..3199

    const float4* p4 = (const float4*)partial;
    float4 sum = make_float4(0.f, 0.f, 0.f, 0.f);
#pragma unroll 4
    for (int b = slice * 16; b < slice * 16 + 16; ++b) {
        float4 v = p4[(size_t)b * CELLS4 + g4];
        sum.x += v.x; sum.y += v.y; sum.z += v.z; sum.w += v.w;
    }
    red[tid] = sum;
    __syncthreads();
    if (tid < 16) {
        float4 tot = red[tid];
#pragma unroll
        for (int p = 1; p < 32; ++p) {
            float4 v = red[p * 16 + tid];
            tot.x += v.x; tot.y += v.y; tot.z += v.z; tot.w += v.w;
        }
        int gg = (g4 * 4) % NG;                 // NG%4==0: never wraps mid-f4
        float4 b1 = *(const float4*)(bi + gg);
        float4 b2 = *(const float4*)(bh + gg);
        tot.x += b1.x + b2.x; tot.y += b1.y + b2.y;
        tot.z += b1.z + b2.z; tot.w += b1.w + b2.w;
        ((float4*)gates)[g4] = tot;
    }
}

__global__ __launch_bounds__(256) void k3_lstm(
    const float* __restrict__ gates, const float* __restrict__ Wh,
    float* __restrict__ out)
{
    __shared__ float gz[CELLS];     // 51.2 KB: all gate pre-activations
    __shared__ float h_lds[64];
    __shared__ float act_lds[NG];
    const int g = threadIdx.x;      // gate index, active < 200

    for (int i = g; i < CELLS; i += 256) gz[i] = gates[i];

    float wh[50];
    if (g < NG) {
#pragma unroll
        for (int j = 0; j < 50; ++j) wh[j] = Wh[j * NG + g];  // coalesced column
    }
    if (g < 64) h_lds[g] = 0.f;
    float c = 0.f, h = 0.f;
    const bool is_cell_gate = (g >= 100 && g < 150);
    __syncthreads();

    for (int s = 0; s < 64; ++s) {
        if (g < NG) {
            float a0 = gz[s * NG + g], a1 = 0.f, a2 = 0.f, a3 = 0.f;
#pragma unroll
            for (int jj = 0; jj < 48; jj += 4) {               // 12x b128 broadcast
                float4 h4 = *(const float4*)(h_lds + jj);
                a0 = fmaf(h4.x, wh[jj],     a0);
                a1 = fmaf(h4.y, wh[jj + 1], a1);
                a2 = fmaf(h4.z, wh[jj + 2], a2);
                a3 = fmaf(h4.w, wh[jj + 3], a3);
            }
            {
                float2 h2 = *(const float2*)(h_lds + 48);      // 1x b64
                a0 = fmaf(h2.x, wh[48], a0);
                a1 = fmaf(h2.y, wh[49], a1);
            }
            float z = (a0 + a1) + (a2 + a3);
            float e   = __expf(-z);
            float sig = 1.f / (1.f + e);
            float e2  = e * e;                        // e^{-2z}
            float th  = (1.f - e2) / (1.f + e2);
            act_lds[g] = is_cell_gate ? th : sig;
        }
        __syncthreads();
        if (g < 50) {
            float iv = act_lds[g];
            float fv = act_lds[50 + g];
            float gv = act_lds[100 + g];
            float ov = act_lds[150 + g];
            c = fmaf(fv, c, iv * gv);
            float e2c = __expf(-2.f * c);
            h = ov * (1.f - e2c) / (1.f + e2c);
            h_lds[g] = h;
        }
        __syncthreads();
    }
    if (g < 50) out[g] = h;
}

extern "C" void kernel_launch(void* const* d_in, const int* in_sizes, int n_in,
                              void* d_out, int out_size, void* d_ws, size_t ws_size,
                              hipStream_t stream)
{
    const float* x  = (const float*)d_in[0];
    const float* Wi = (const float*)d_in[1];
    const float* bi = (const float*)d_in[2];
    const float* Wh = (const float*)d_in[3];
    const float* bh = (const float*)d_in[4];
    float* out = (float*)d_out;

    float* partial = (float*)d_ws;                    // 512*12800 f32 = 26.2 MB
    float* gates   = partial + (size_t)NBLK * CELLS;  // 12800 f32

    k1_gemm_partial<<<NBLK, 256, 0, stream>>>(x, Wi, partial);
    k2_reduce<<<CELLS4 / 16, 512, 0, stream>>>(partial, bi, bh, gates);
    k3_lstm<<<1, 256, 0, stream>>>(gates, Wh, out);
}

// Round 7
// 187.770 us; speedup vs baseline: 1.1108x; 1.0044x over previous
//
#include <hip/hip_runtime.h>
#include <hip/hip_bf16.h>

// LSTM: SEQ=64, IN=100000, H=50 (4H=200 gates)
// x[64,100000] f32, Wi[100000,200] f32, bi[200], Wh[50,200], bh[200] -> h[50]
//
// K1: split-K GEMM via MFMA 32x32x16 bf16, hi/lo-split fp32 emulation
//     (f = bf16hi + bf16lo; x*w = xh*wh + xh*wl + xl*wh, ~2^-17 rel err).
//     R7: NBLK 256 x 512 thr (was 512 x 256) -> partial traffic halved
//     (26.2 -> 13.1 MB each way), same waves-in-flight per CU.
//     8 waves: wave = stile*4 + gset; gset owns g-tiles {2g, 2g+1};
//     gset3 second tile dups tile 6 (no OOB), store skipped.
// K2: reduce 256 partials + bi + bh -> gates[s*200+g]
// K3: 64-step recurrence, single block, gates in LDS.

#define K_DIM 100000
#define NG 200
#define NS 64
#define TK 32                    // 100000 = 32 * 3125 exactly
#define NBLK 256
#define NTILES 3125              // K_DIM / TK
#define CELLS (NS * NG)          // 12800
#define CELLS4 (CELLS / 4)       // 3200
#define ROWU 40                  // u16 per LDS row = 32 k + 8 pad = 80 B (16B-aligned)

typedef unsigned short u16;
typedef unsigned int   u32;
typedef __bf16 bf16x8 __attribute__((ext_vector_type(8)));
typedef float  f32x16 __attribute__((ext_vector_type(16)));

static __device__ __forceinline__ u32 rne16(float f) {
    u32 u = __float_as_uint(f);
    return (u + 0x7FFFu + ((u >> 16) & 1u)) >> 16;
}
static __device__ __forceinline__ void split_hl(float f, u32& h, u32& l) {
    u32 u  = __float_as_uint(f);
    u32 hb = u & 0xFFFF0000u;
    h = hb >> 16;
    l = rne16(f - __uint_as_float(hb));   // remainder exact; rne to bf16
}
static __device__ __forceinline__ void split4(float4 v, u32 h[4], u32 l[4]) {
    split_hl(v.x, h[0], l[0]); split_hl(v.y, h[1], l[1]);
    split_hl(v.z, h[2], l[2]); split_hl(v.w, h[3], l[3]);
}
static __device__ __forceinline__ f32x16 mfma_bf(uint4 a, uint4 b, f32x16 c) {
    return __builtin_amdgcn_mfma_f32_32x32x16_bf16(
        __builtin_bit_cast(bf16x8, a), __builtin_bit_cast(bf16x8, b), c, 0, 0, 0);
}

__global__ __launch_bounds__(512, 1) void k1_gemm_partial(
    const float* __restrict__ x, const float* __restrict__ Wi,
    float* __restrict__ partial)
{
    __shared__ __align__(16) u16 WH[224 * ROWU];   // Wi hi, [g][k]  17.9 KB
    __shared__ __align__(16) u16 WL[224 * ROWU];   // Wi lo
    __shared__ __align__(16) u16 XH[64 * ROWU];    // x  hi, [s][k]   5.1 KB
    __shared__ __align__(16) u16 XL[64 * ROWU];    // x  lo          total 46 KB

    const int t    = threadIdx.x;
    const int lane = t & 63;
    const int wave = t >> 6;             // 0..7
    const int m    = lane & 31;          // MFMA row/col within tile
    const int h    = lane >> 5;          // k-half
    const int stile = wave >> 2;         // 0..1
    const int gset  = wave & 3;          // g-tiles {2g, 2g+1}; gset3: {6, dup6}

    // zero Wi pad rows 200..223 once
    {
        u32* zh = (u32*)&WH[200 * ROWU];
        u32* zl = (u32*)&WL[200 * ROWU];
        for (int i = t; i < 24 * ROWU / 2; i += 512) { zh[i] = 0; zl[i] = 0; }
    }

    // Wi staging: 400 f4-tasks (g4 0..49 x k4 0..7), threads t<400
    const int a_g4 = t >> 3;
    const int a_k4 = t & 7;
    const bool has_w = (t < 400);
    // x staging: 512 f4-tasks (s 0..63 x k4 0..7), one per thread
    const int xs0 = t >> 3, xk0 = t & 7;

    float4 wa[4], xa;
    auto do_loads = [&](int ti) {
        const size_t kt = (size_t)ti * TK;
        if (has_w) {
#pragma unroll
            for (int j = 0; j < 4; ++j)
                wa[j] = *(const float4*)(Wi + (kt + a_k4 * 4 + j) * NG + a_g4 * 4);
        }
        xa = *(const float4*)(x + (size_t)xs0 * K_DIM + kt + xk0 * 4);
    };
    auto stage_wi = [&](const float4 r[4], int g4, int k4) {
        u32 hw[4][4], lw[4][4];
#pragma unroll
        for (int j = 0; j < 4; ++j) split4(r[j], hw[j], lw[j]);
#pragma unroll
        for (int j2 = 0; j2 < 4; ++j2) {   // transpose: row g=4g4+j2 gets 4 k's
            int off = (4 * g4 + j2) * ROWU + k4 * 4;
            *(uint2*)&WH[off] = make_uint2(hw[0][j2] | (hw[1][j2] << 16),
                                           hw[2][j2] | (hw[3][j2] << 16));
            *(uint2*)&WL[off] = make_uint2(lw[0][j2] | (lw[1][j2] << 16),
                                           lw[2][j2] | (lw[3][j2] << 16));
        }
    };
    auto stage_x = [&](float4 v, int s, int k4) {
        u32 hh[4], ll[4];
        split4(v, hh, ll);
        int off = s * ROWU + k4 * 4;
        *(uint2*)&XH[off] = make_uint2(hh[0] | (hh[1] << 16), hh[2] | (hh[3] << 16));
        *(uint2*)&XL[off] = make_uint2(ll[0] | (ll[1] << 16), ll[2] | (ll[3] << 16));
    };

    f32x16 acc[2];
#pragma unroll
    for (int tt = 0; tt < 2; ++tt)
#pragma unroll
        for (int r = 0; r < 16; ++r) acc[tt][r] = 0.f;

    // fragment LDS offsets (u16 units)
    const int aoff = (stile * 32 + m) * ROWU + h * 8;
    int boff[2];
#pragma unroll
    for (int tt = 0; tt < 2; ++tt) {
        int gt = (gset == 3 && tt == 1) ? 6 : (2 * gset + tt);
        boff[tt] = (gt * 32 + m) * ROWU + h * 8;
    }

    do_loads(blockIdx.x);
    for (int ti = blockIdx.x; ti < NTILES; ti += NBLK) {
        __syncthreads();                 // previous stage's frag readers done
        if (has_w) stage_wi(wa, a_g4, a_k4);
        stage_x(xa, xs0, xk0);
        __syncthreads();

        int tin = ti + NBLK;
        if (tin < NTILES) do_loads(tin); // latency hides behind MFMA phase

#pragma unroll
        for (int kk = 0; kk < 2; ++kk) {
            uint4 ah = *(const uint4*)&XH[aoff + kk * 16];
            uint4 al = *(const uint4*)&XL[aoff + kk * 16];
#pragma unroll
            for (int tt = 0; tt < 2; ++tt) {
                uint4 bh = *(const uint4*)&WH[boff[tt] + kk * 16];
                uint4 bl = *(const uint4*)&WL[boff[tt] + kk * 16];
                acc[tt] = mfma_bf(ah, bh, acc[tt]);   // xh*wh
                acc[tt] = mfma_bf(ah, bl, acc[tt]);   // xh*wl
                acc[tt] = mfma_bf(al, bh, acc[tt]);   // xl*wh
            }
        }
    }

    // epilogue: partial[b][s][g]; C/D: col=lane&31, row=(r&3)+8(r>>2)+4h
    float* base = partial + (size_t)blockIdx.x * CELLS;
#pragma unroll
    for (int tt = 0; tt < 2; ++tt) {
        if (gset == 3 && tt == 1) continue;   // duplicate of tile 6
        int g = (2 * gset + tt) * 32 + m;
        if (g < NG) {
#pragma unroll
            for (int r = 0; r < 16; ++r) {
                int srow = stile * 32 + (r & 3) + 8 * (r >> 2) + 4 * h;
                base[srow * NG + g] = acc[tt][r];
            }
        }
    }
}

__global__ __launch_bounds__(512) void k2_reduce(
    const float* __restrict__ partial, const float* __restrict__ bi,
    const float* __restrict__ bh, float* __restrict__ gates)
{
    __shared__ float4 red[512];
    const int tid   = threadIdx.x;
    const int fid   = tid & 15;                 // f4-cell within block
    const int slice = tid >> 4;                 // 0..31, each sums 8 b's
    const int g4    = blockIdx.x * 16 + fid;    // 0..3199

    const float4* p4 = (const float4*)partial;
    float4 sum = make_float4(0.f, 0.f, 0.f, 0.f);
#pragma unroll 4
    for (int b = slice * 8; b < slice * 8 + 8; ++b) {
        float4 v = p4[(size_t)b * CELLS4 + g4];
        sum.x += v.x; sum.y += v.y; sum.z += v.z; sum.w += v.w;
    }
    red[tid] = sum;
    __syncthreads();
    if (tid < 16) {
        float4 tot = red[tid];
#pragma unroll
        for (int p = 1; p < 32; ++p) {
            float4 v = red[p * 16 + tid];
            tot.x += v.x; tot.y += v.y; tot.z += v.z; tot.w += v.w;
        }
        int gg = (g4 * 4) % NG;                 // NG%4==0: never wraps mid-f4
        float4 b1 = *(const float4*)(bi + gg);
        float4 b2 = *(const float4*)(bh + gg);
        tot.x += b1.x + b2.x; tot.y += b1.y + b2.y;
        tot.z += b1.z + b2.z; tot.w += b1.w + b2.w;
        ((float4*)gates)[g4] = tot;
    }
}

__global__ __launch_bounds__(256) void k3_lstm(
    const float* __restrict__ gates, const float* __restrict__ Wh,
    float* __restrict__ out)
{
    __shared__ float gz[CELLS];     // 51.2 KB: all gate pre-activations
    __shared__ float h_lds[64];
    __shared__ float act_lds[NG];
    const int g = threadIdx.x;      // gate index, active < 200

    for (int i = g; i < CELLS; i += 256) gz[i] = gates[i];

    float wh[50];
    if (g < NG) {
#pragma unroll
        for (int j = 0; j < 50; ++j) wh[j] = Wh[j * NG + g];  // coalesced column
    }
    if (g < 64) h_lds[g] = 0.f;
    float c = 0.f, h = 0.f;
    const bool is_cell_gate = (g >= 100 && g < 150);
    __syncthreads();

    for (int s = 0; s < 64; ++s) {
        if (g < NG) {
            float a0 = gz[s * NG + g], a1 = 0.f, a2 = 0.f, a3 = 0.f;
#pragma unroll
            for (int jj = 0; jj < 48; jj += 4) {               // 12x b128 broadcast
                float4 h4 = *(const float4*)(h_lds + jj);
                a0 = fmaf(h4.x, wh[jj],     a0);
                a1 = fmaf(h4.y, wh[jj + 1], a1);
                a2 = fmaf(h4.z, wh[jj + 2], a2);
                a3 = fmaf(h4.w, wh[jj + 3], a3);
            }
            {
                float2 h2 = *(const float2*)(h_lds + 48);      // 1x b64
                a0 = fmaf(h2.x, wh[48], a0);
                a1 = fmaf(h2.y, wh[49], a1);
            }
            float z = (a0 + a1) + (a2 + a3);
            float e   = __expf(-z);
            float sig = 1.f / (1.f + e);
            float e2  = e * e;                        // e^{-2z}
            float th  = (1.f - e2) / (1.f + e2);
            act_lds[g] = is_cell_gate ? th : sig;
        }
        __syncthreads();
        if (g < 50) {
            float iv = act_lds[g];
            float fv = act_lds[50 + g];
            float gv = act_lds[100 + g];
            float ov = act_lds[150 + g];
            c = fmaf(fv, c, iv * gv);
            float e2c = __expf(-2.f * c);
            h = ov * (1.f - e2c) / (1.f + e2c);
            h_lds[g] = h;
        }
        __syncthreads();
    }
    if (g < 50) out[g] = h;
}

extern "C" void kernel_launch(void* const* d_in, const int* in_sizes, int n_in,
                              void* d_out, int out_size, void* d_ws, size_t ws_size,
                              hipStream_t stream)
{
    const float* x  = (const float*)d_in[0];
    const float* Wi = (const float*)d_in[1];
    const float* bi = (const float*)d_in[2];
    const float* Wh = (const float*)d_in[3];
    const float* bh = (const float*)d_in[4];
    float* out = (float*)d_out;

    float* partial = (float*)d_ws;                    // 256*12800 f32 = 13.1 MB
    float* gates   = partial + (size_t)NBLK * CELLS;  // 12800 f32

    k1_gemm_partial<<<NBLK, 512, 0, stream>>>(x, Wi, partial);
    k2_reduce<<<CELLS4 / 16, 512, 0, stream>>>(partial, bi, bh, gates);
    k3_lstm<<<1, 256, 0, stream>>>(gates, Wh, out);
}